// Round 8
// baseline (357.164 us; speedup 1.0000x reference)
//
#include <hip/hip_runtime.h>
#include <hip/hip_fp16.h>
#include <math.h>

// SSL compressor gain: 128 independent nonlinear 2-state IIR chains, T=131072.
// Round 8: (r7 structure) map -> interp guesses -> 3x Newton(jac+affine
// compose) at CF=256 -> out.
//   - map DECIMATED 2x (pair-averaged x, squared coefs): guesses only need
//     ~0.1 dB fidelity; map cost 86 -> ~48us (issue-throughput bound).
//   - CF 512->256: fine passes ~2x faster; contraction coef <=0.43 (r6).
//   - 3rd Newton iter absorbs decimation error: d0~1.0 -> d1~0.5 -> d2~0.1
//     -> d3 ~ floor (f32 noise 0.06).
//   - params hoisted to a 1-thread kernel (9 double exps were serial prologue
//     in every latency-bound wave); map table stored as half2.

constexpr int   T_LEN    = 131072;
constexpr int   NCM      = 64;              // coarse map chunks
constexpr int   CM       = T_LEN / NCM;     // 2048 samples
constexpr int   SUB      = 8;               // snapshots per map chunk (every 256)
constexpr int   NC       = NCM * SUB;       // 512 fine chunks
constexpr int   CF       = T_LEN / NC;      // 256 samples
constexpr int   K        = 16;              // ES nodes: 0 .. -8, h=8/15
constexpr float STEP_ES  = 8.0f / 15.0f;
constexpr float INV_STEP = 15.0f / 8.0f;
constexpr int   DPF      = 8;               // float4 prefetch depth
constexpr int   NV_ROW   = T_LEN >> 2;

// pw layout: 0 nhs, 1 hst, 2 nq, 3 r, 4 a_af, 5 a_as, 6 a_sf, 7 a_ss,
//            8 d_af, 9 d_as, 10 d_sf, 11 d_ss, 12 nhs_h (=0.5*nhs)
__global__ void ssl_params_k(
        float* __restrict__ pw,
        const float* cth, const float* rl, const float* fbl,
        const float* uaf, const float* uas, const float* usf, const float* uss)
{
    const double FS = 44100.0;
    const double T_AF_MIN = 820.0 * 4.7e-07 * 0.8,   T_AF_MAX = 270000.0 * 4.7e-07 * 1.2;
    const double T_AS_MIN = 820.0 * 6.8e-06 * 0.8,   T_AS_MAX = 270000.0 * 6.8e-06 * 100.0;
    const double T_SF_MIN = 91000.0 * 4.7e-07 * 0.8, T_SF_MAX = 1200000.0 * 4.7e-07 * 1.2;
    const double T_SS_MIN = 750000.0 * 6.8e-06 * 0.8, T_SS_MAX = 750000.0 * 6.8e-06 * 100.0;

    double cr    = fmax(exp((double)rl[0]) + 1.0, 1.0 + 1e-4);
    double fb    = 1.0 / (1.0 + exp(-(double)fbl[0]));
    double slope = 1.0 - 1.0 / cr;

    double s_af = T_AF_MIN + (T_AF_MAX - T_AF_MIN) / (1.0 + exp(-(double)uaf[0]));
    double s_as = T_AS_MIN + (T_AS_MAX - T_AS_MIN) / (1.0 + exp(-(double)uas[0]));
    double s_sf = T_SF_MIN + (T_SF_MAX - T_SF_MIN) / (1.0 + exp(-(double)usf[0]));
    double s_ss = T_SS_MIN + (T_SS_MAX - T_SS_MIN) / (1.0 + exp(-(double)uss[0]));

    float a_af = (float)exp(-1.0 / (FS * s_af));
    float a_as = (float)exp(-1.0 / (FS * s_as));
    float a_sf = (float)exp(-1.0 / (FS * s_sf));
    float a_ss = (float)exp(-1.0 / (FS * s_ss));
    double q = 0.5 * slope * fb;

    pw[0]  = (float)(-0.5 * slope);                  // nhs
    pw[1]  = (float)(0.5 * slope * (double)cth[0]);  // hst
    pw[2]  = (float)(-q);                            // nq
    pw[3]  = (float)(0.5 + q);                       // r
    pw[4]  = a_af;  pw[5] = a_as;  pw[6] = a_sf;  pw[7] = a_ss;
    pw[8]  = a_af * a_af;  pw[9]  = a_as * a_as;     // decimated coefs
    pw[10] = a_sf * a_sf;  pw[11] = a_ss * a_ss;
    pw[12] = (float)(-0.25 * slope);                 // nhs_h (0.5*nhs, pair avg)
}

// Pass 1: decimated diagonal chunk maps at K ES-nodes, SUB snapshots/node.
// Each float4 = 2 decimated steps (pair-averaged input, squared coefs).
__global__ __launch_bounds__(256) void ssl_map(
        const float* __restrict__ x, __half2* __restrict__ mp,
        const float* __restrict__ pw, int B)
{
    int tid = blockIdx.x * 256 + threadIdx.x;
    int k  = tid & (K - 1);
    int bc = tid >> 4;                       // b*NCM + c
    if (bc >= B * NCM) return;
    int c  = bc & (NCM - 1);
    int b  = bc >> 6;                        // NCM = 64

    const float nhs_h = pw[12], hst = pw[1], nq = pw[2], r = pw[3];
    const float d_af = pw[8], d_as = pw[9], d_sf = pw[10], d_ss = pw[11];

    float v0s = -STEP_ES * (float)k;
    float EF = v0s, ES = v0s, Y = EF + ES;
    const float4* __restrict__ xr = reinterpret_cast<const float4*>(x + (size_t)b * T_LEN);
    const int v0 = c * (CM >> 2);            // 512 float4s per coarse chunk

    float4 buf[DPF];
    #pragma unroll
    for (int i = 0; i < DPF; ++i) buf[i] = xr[v0 + i];

    #pragma unroll 1
    for (int q8 = 0; q8 < SUB; ++q8) {
        const int s0 = v0 + q8 * (CF >> 2);  // 64 float4s per sub-segment
        for (int v = s0; v < s0 + (CF >> 2); v += DPF) {
            #pragma unroll
            for (int i = 0; i < DPF; ++i) {
                float4 xv = buf[i];
                int nxt = v + DPF + i;
                if (nxt < NV_ROW) buf[i] = xr[nxt];
#define DEC_STEP(X0, X1) { \
                float sx2 = fmaf(nhs_h, (X0), fmaf(nhs_h, (X1), hst)); \
                float u2  = fmaf(nq, Y, sx2); \
                float t2  = fminf(u2, 0.0f); \
                bool att  = sx2 < r * Y; \
                float af  = att ? d_af : d_sf; \
                float as2 = att ? d_as : d_ss; \
                EF = fmaf(af,  EF - t2, t2); \
                ES = fmaf(as2, ES - t2, t2); \
                Y  = EF + ES; }
                DEC_STEP(xv.x, xv.y)
                DEC_STEP(xv.z, xv.w)
#undef DEC_STEP
            }
        }
        mp[((size_t)bc * SUB + q8) * K + k] = __floats2half2_rn(EF, ES);
    }
}

// Pass 2: serial interp compose -> initial guesses at all NC fine boundaries.
__global__ __launch_bounds__(64) void ssl_compose0(
        const __half2* __restrict__ mp, float2* __restrict__ bnd0, int B)
{
    int b = blockIdx.x * 64 + threadIdx.x;
    if (b >= B) return;
    float EF = 0.0f, ES = 0.0f;
    for (int c = 0; c < NCM; ++c) {
        int bc = b * NCM + c;
        bnd0[b * NC + SUB * c] = make_float2(EF, ES);
        float t = -ES * INV_STEP;
        int idx = (int)t;
        idx = idx < 0 ? 0 : (idx > K - 2 ? K - 2 : idx);
        float u = t - (float)idx;
        const __half2* m = &mp[(size_t)bc * SUB * K];
        #pragma unroll
        for (int q = 0; q < SUB; ++q) {
            float2 a0 = __half22float2(m[q * K + idx]);
            float2 a1 = __half22float2(m[q * K + idx + 1]);
            float gx = a0.x + (a1.x - a0.x) * u;
            float gy = a0.y + (a1.y - a0.y) * u;
            if (q < SUB - 1) bnd0[b * NC + SUB * c + 1 + q] = make_float2(gx, gy);
            else { EF = gx; ES = gy; }
        }
    }
}

// Jac pass: exact runs from guesses with forward-mode 2x2 Jacobian
// (exact conditioned on realized gates); emit affine form (J, g = F - J*s0).
__global__ __launch_bounds__(64) void ssl_jac(
        const float* __restrict__ x,
        const float2* __restrict__ bndin,
        float4* __restrict__ Jv, float2* __restrict__ gv,
        const float* __restrict__ pw, int B)
{
    int tid = blockIdx.x * 64 + threadIdx.x;
    int b = tid & 127;                        // B = 128
    int c = tid >> 7;
    if (c >= NC) return;

    const float nhs = pw[0], hst = pw[1], nq = pw[2], r = pw[3];
    const float a_af = pw[4], a_as = pw[5], a_sf = pw[6], a_ss = pw[7];

    float2 s0 = bndin[b * NC + c];
    float EF = s0.x, ES = s0.y, Y = EF + ES;
    float jFx = 1.0f, jFy = 0.0f, jSx = 0.0f, jSy = 1.0f;

    const float4* __restrict__ xr = reinterpret_cast<const float4*>(x + (size_t)b * T_LEN);
    const int v0 = c * (CF >> 2), v1 = v0 + (CF >> 2);

    float4 buf[DPF];
    #pragma unroll
    for (int i = 0; i < DPF; ++i) buf[i] = xr[v0 + i];

    for (int v = v0; v < v1; v += DPF) {
        #pragma unroll
        for (int i = 0; i < DPF; ++i) {
            float4 xv = buf[i];
            int nxt = v + DPF + i;
            if (nxt < NV_ROW) buf[i] = xr[nxt];
#define SSL_STEP_J(XV) { \
            float sx2 = fmaf(nhs, (XV), hst); \
            float u2  = fmaf(nq, Y, sx2); \
            float t2  = fminf(u2, 0.0f); \
            bool g2   = u2 < 0.0f; \
            bool att  = sx2 < r * Y; \
            float af  = att ? a_af : a_sf; \
            float as2 = att ? a_as : a_ss; \
            float jYx = jFx + jSx, jYy = jFy + jSy; \
            float jtx = g2 ? nq * jYx : 0.0f; \
            float jty = g2 ? nq * jYy : 0.0f; \
            jFx = fmaf(af,  jFx - jtx, jtx); \
            jFy = fmaf(af,  jFy - jty, jty); \
            jSx = fmaf(as2, jSx - jtx, jtx); \
            jSy = fmaf(as2, jSy - jty, jty); \
            EF  = fmaf(af,  EF - t2, t2); \
            ES  = fmaf(as2, ES - t2, t2); \
            Y   = EF + ES; }
            SSL_STEP_J(xv.x)
            SSL_STEP_J(xv.y)
            SSL_STEP_J(xv.z)
            SSL_STEP_J(xv.w)
#undef SSL_STEP_J
        }
    }
    Jv[b * NC + c] = make_float4(jFx, jFy, jSx, jSy);
    gv[b * NC + c] = make_float2(EF - (jFx * s0.x + jFy * s0.y),
                                 ES - (jSx * s0.x + jSy * s0.y));
}

// Affine compose: s_{c+1} = J_c*s_c + g_c. Statically-addressed loads pipeline.
__global__ __launch_bounds__(64) void ssl_compose1(
        const float4* __restrict__ Jv, const float2* __restrict__ gv,
        float2* __restrict__ bndout, int B)
{
    int b = blockIdx.x * 64 + threadIdx.x;
    if (b >= B) return;
    const float4* Jr = Jv + (size_t)b * NC;
    const float2* gr = gv + (size_t)b * NC;
    float2* br = bndout + (size_t)b * NC;
    float sx = 0.0f, sy = 0.0f;
    #pragma unroll 8
    for (int c = 0; c < NC; ++c) {
        br[c] = make_float2(sx, sy);
        float4 J = Jr[c];
        float2 g = gr[c];
        float nx = g.x + J.x * sx + J.y * sy;
        float ny = g.y + J.z * sx + J.w * sy;
        sx = nx; sy = ny;
    }
}

// Out pass: rerun each fine chunk from its corrected boundary state, store y.
__global__ __launch_bounds__(64) void ssl_out(
        const float* __restrict__ x, float* __restrict__ out,
        const float2* __restrict__ bnd,
        const float* __restrict__ pw, int B)
{
    int tid = blockIdx.x * 64 + threadIdx.x;
    int b = tid & 127;
    int c = tid >> 7;
    if (c >= NC) return;

    const float nhs = pw[0], hst = pw[1], nq = pw[2], r = pw[3];
    const float a_af = pw[4], a_as = pw[5], a_sf = pw[6], a_ss = pw[7];

    float2 s = bnd[b * NC + c];
    float EF = s.x, ES = s.y, Y = EF + ES;
    const float4* __restrict__ xr = reinterpret_cast<const float4*>(x + (size_t)b * T_LEN);
    float4* __restrict__ yr       = reinterpret_cast<float4*>(out + (size_t)b * T_LEN);
    const int v0 = c * (CF >> 2), v1 = v0 + (CF >> 2);

    float4 buf[DPF];
    #pragma unroll
    for (int i = 0; i < DPF; ++i) buf[i] = xr[v0 + i];

    for (int v = v0; v < v1; v += DPF) {
        #pragma unroll
        for (int i = 0; i < DPF; ++i) {
            float4 xv = buf[i];
            int nxt = v + DPF + i;
            if (nxt < NV_ROW) buf[i] = xr[nxt];
            float4 yo;
#define SSL_STEP(XV, YOUT) { \
            float sx2 = fmaf(nhs, (XV), hst); \
            float u2  = fmaf(nq, Y, sx2); \
            float t2  = fminf(u2, 0.0f); \
            bool att  = sx2 < r * Y; \
            float af  = att ? a_af : a_sf; \
            float as2 = att ? a_as : a_ss; \
            EF = fmaf(af,  EF - t2, t2); \
            ES = fmaf(as2, ES - t2, t2); \
            Y  = EF + ES; \
            (YOUT) = Y; }
            SSL_STEP(xv.x, yo.x)
            SSL_STEP(xv.y, yo.y)
            SSL_STEP(xv.z, yo.z)
            SSL_STEP(xv.w, yo.w)
#undef SSL_STEP
            yr[v + i] = yo;
        }
    }
}

extern "C" void kernel_launch(void* const* d_in, const int* in_sizes, int n_in,
                              void* d_out, int out_size, void* d_ws, size_t ws_size,
                              hipStream_t stream) {
    const float* x = (const float*)d_in[0];
    const int B = in_sizes[0] / T_LEN;   // 128
    const int NCt = B * NC;              // 65536 fine chunks total

    // ws layout (16B-aligned blocks first)
    float4*  Jv   = (float4*)d_ws;                         // [B][NC]      1 MB
    __half2* mp   = (__half2*)(Jv + (size_t)NCt);          // [B*NCM][SUB][K] 4 MB
    float2*  bndA = (float2*)(mp + (size_t)B * NCM * SUB * K); // [B][NC]  0.5 MB
    float2*  bndB = bndA + (size_t)NCt;                    // [B][NC]      0.5 MB
    float2*  gv   = bndB + (size_t)NCt;                    // [B][NC]      0.5 MB
    float*   pw   = (float*)(gv + (size_t)NCt);            // 16 floats

    ssl_params_k<<<1, 1, 0, stream>>>(
        pw,
        (const float*)d_in[1], (const float*)d_in[2], (const float*)d_in[3],
        (const float*)d_in[4], (const float*)d_in[5], (const float*)d_in[6],
        (const float*)d_in[7]);

    int map_threads = B * NCM * K;       // 131072
    ssl_map<<<(map_threads + 255) / 256, 256, 0, stream>>>(x, mp, pw, B);

    ssl_compose0<<<(B + 63) / 64, 64, 0, stream>>>(mp, bndA, B);

    // Newton iteration 1: bndA -> bndB
    ssl_jac<<<(NCt + 63) / 64, 64, 0, stream>>>(x, bndA, Jv, gv, pw, B);
    ssl_compose1<<<(B + 63) / 64, 64, 0, stream>>>(Jv, gv, bndB, B);

    // Newton iteration 2: bndB -> bndA
    ssl_jac<<<(NCt + 63) / 64, 64, 0, stream>>>(x, bndB, Jv, gv, pw, B);
    ssl_compose1<<<(B + 63) / 64, 64, 0, stream>>>(Jv, gv, bndA, B);

    // Newton iteration 3: bndA -> bndB
    ssl_jac<<<(NCt + 63) / 64, 64, 0, stream>>>(x, bndA, Jv, gv, pw, B);
    ssl_compose1<<<(B + 63) / 64, 64, 0, stream>>>(Jv, gv, bndB, B);

    ssl_out<<<(NCt + 63) / 64, 64, 0, stream>>>(x, (float*)d_out, bndB, pw, B);
}